// Round 1
// baseline (453.684 us; speedup 1.0000x reference)
//
#include <hip/hip_runtime.h>

// SpikeLayer: V_{t} = reset(V_{t-1} + I_t), reset(x) = (|x|>1 ? 0 : x)
// inputs: [T*B, D] fp32 with T=16, B=512, D=8192. Output same shape, out_t = V_t.
// Each (b,d) position is an independent length-16 serial chain; stride between
// steps is B*D elements. Memory-bound: 512 MB total traffic -> ~81 us floor.

constexpr int TIMES = 16;
constexpr long long STEP_F4 = (512LL * 8192LL) / 4;  // float4 elems per t-slice = 1048576

__global__ __launch_bounds__(256) void SpikeLayer_88553635709313_kernel(
    const float4* __restrict__ in, float4* __restrict__ out) {
    long long idx = (long long)blockIdx.x * blockDim.x + threadIdx.x;  // [0, STEP_F4)
    float4 V = make_float4(0.f, 0.f, 0.f, 0.f);
    long long p = idx;
#pragma unroll
    for (int t = 0; t < TIMES; ++t) {
        float4 I = in[p];
        V.x += I.x; V.y += I.y; V.z += I.z; V.w += I.w;
        V.x = (fabsf(V.x) > 1.0f) ? 0.0f : V.x;
        V.y = (fabsf(V.y) > 1.0f) ? 0.0f : V.y;
        V.z = (fabsf(V.z) > 1.0f) ? 0.0f : V.z;
        V.w = (fabsf(V.w) > 1.0f) ? 0.0f : V.w;
        out[p] = V;
        p += STEP_F4;
    }
}

extern "C" void kernel_launch(void* const* d_in, const int* in_sizes, int n_in,
                              void* d_out, int out_size, void* d_ws, size_t ws_size,
                              hipStream_t stream) {
    const float4* in = (const float4*)d_in[0];
    float4* out = (float4*)d_out;
    const int threads = 256;
    const int blocks = (int)(STEP_F4 / threads);  // 4096
    SpikeLayer_88553635709313_kernel<<<blocks, threads, 0, stream>>>(in, out);
}